// Round 12
// baseline (694.250 us; speedup 1.0000x reference)
//
#include <hip/hip_runtime.h>
#include <hip/hip_bf16.h>

// WorkflowGNN: GCN(32->64)+ReLU, GAT(64->64,h=1)+ReLU, GCN(64->64)+ReLU,
// heads: opt [N,10], bottleneck [N,1], mean-embed [64]. f32 in/out.
// R11->R12: k_hist was the sole top-5 resident (62us, WRITE 50MB vs 8MB
// ideal): blockIdx&7->XCD assumption only partially holds, so slice windows
// replicate dirty across L2s. Now blocks read HW_REG_XCC_ID (real XCD id,
// m09-verified) and drain their own slice's chunk queue (atomic tickets),
// stealing other slices when done -> correct under ANY dispatch mapping,
// locality exact when mapping is sane. init/cast/pack fused into k_setup.

#define CAP 64
#define HCHUNK 1024

__device__ __forceinline__ int uwave(){                 // wave id, known-uniform
  return __builtin_amdgcn_readfirstlane(threadIdx.x >> 6);
}
__device__ __forceinline__ int xcc_id(){                // real XCD id 0..7
  int x;
  asm volatile("s_getreg_b32 %0, hwreg(HW_REG_XCC_ID)" : "=s"(x));
  return x & 7;
}
__device__ __forceinline__ unsigned short f2bf(float f){ // RNE, finite inputs
  unsigned u = __float_as_uint(f);
  return (unsigned short)((u + 0x7fffu + ((u >> 16) & 1u)) >> 16);
}
__device__ __forceinline__ float bfl(unsigned u){ return __uint_as_float(u << 16); }
__device__ __forceinline__ float bfh(unsigned u){ return __uint_as_float(u & 0xffff0000u); }

// fused setup: zero cnt/tickets/pad-row/emb_acc, cast x->bf16, pack Wcat/bcat
__global__ void k_setup(const float* __restrict__ x, unsigned short* __restrict__ xh,
                        const float* __restrict__ Wopt, const float* __restrict__ bopt,
                        const float* __restrict__ Wb1, const float* __restrict__ bb1,
                        float* __restrict__ Wcat, float* __restrict__ bcat,
                        int* __restrict__ cnt, unsigned short* __restrict__ tb,
                        float* __restrict__ emb_acc, int* __restrict__ ticket,
                        int n, int total4){
  int i = blockIdx.x*blockDim.x + threadIdx.x;
  if (i < total4){                            // cast x (f32x4 -> bf16x4)
    float4 v = ((const float4*)x)[i];
    uint2 o;
    o.x = (unsigned)f2bf(v.x) | ((unsigned)f2bf(v.y) << 16);
    o.y = (unsigned)f2bf(v.z) | ((unsigned)f2bf(v.w) << 16);
    ((uint2*)xh)[i] = o;
  }
  if (i < n) cnt[i] = 0;
  if (blockIdx.x == 0){
    int tid = threadIdx.x;
    for (int j = tid; j < 4096; j += 256){    // pack head weights
      int f = j >> 6, c = j & 63;
      float w = 0.f;
      if (c < 10)       w = Wopt[f*10 + c];
      else if (c >= 32) w = Wb1[f*32 + (c-32)];
      Wcat[j] = w;
    }
    if (tid < 64){
      float b = 0.f;
      if (tid < 10)       b = bopt[tid];
      else if (tid >= 32) b = bb1[tid-32];
      bcat[tid] = b;
      tb[(size_t)n*64 + tid] = 0;             // zero pad row
      emb_acc[tid] = 0.f;
    }
    if (tid >= 64 && tid < 72) ticket[tid-64] = 0;
  }
}

// XCD-local histogram with work-stealing chunk queues: block drains its own
// XCD's dst-slice first (exact L2 locality), then steals remaining slices.
__global__ __launch_bounds__(256) void k_hist(const int* __restrict__ src,
                       const int* __restrict__ dst, int* __restrict__ cnt,
                       int* __restrict__ adj, int* __restrict__ ticket,
                       int e, int nper, int nchunk){
  __shared__ int ch;
  int xcc = xcc_id();
  int tid = threadIdx.x;
  for (int s0 = 0; s0 < 8; s0++){
    int s = (xcc + s0) & 7;                   // own slice first, then steal
    int lo = s*nper, hi = lo + nper;
    while (true){
      if (tid == 0) ch = atomicAdd(&ticket[s], 1);
      __syncthreads();
      int chunk = ch;
      __syncthreads();
      if (chunk >= nchunk) break;
      int base = chunk*HCHUNK;
      #pragma unroll
      for (int k = 0; k < HCHUNK/256; k++){
        int i = base + k*256 + tid;
        if (i < e){
          int d = __builtin_nontemporal_load(&dst[i]);
          if (d >= lo && d < hi){
            int pos = atomicAdd(&cnt[d], 1);
            if (pos < CAP){
              int sv = __builtin_nontemporal_load(&src[i]);
              adj[(size_t)d*CAP + pos] = sv;
            }
          }
        }
      }
    }
  }
}

// layer-1 aggregate in INPUT space (bf16 x, 64B rows): 8 grp x 8 lanes,
// uint2/lane = 8 rows per instruction. y = dinv_v*(sum dinv_u*x[u] + dinv_v*x[v])
__global__ __launch_bounds__(256) void k_agg32(const unsigned short* __restrict__ xh,
                          const int* __restrict__ adj, const int* __restrict__ cnt,
                          float* __restrict__ y, int n){
  int lane = threadIdx.x & 63;
  int v = blockIdx.x*4 + uwave();
  if (v >= n) return;                         // uniform
  int cn = cnt[v];
  int c = min(cn, CAP);
  const int* row = adj + (size_t)v*CAP;
  int usafe = v;
  if (lane < c) usafe = row[lane];            // exec-masked coalesced
  float wl = (lane < c) ? rsqrtf((float)(cnt[usafe] + 1)) : 0.f;  // dinv_u
  int g = lane >> 3, q = lane & 7;
  float4 acc = {0.f, 0.f, 0.f, 0.f};
  int iters = (c + 7) >> 3;
  for (int jj = 0; jj < iters; jj++){
    int   u = __shfl(usafe, jj*8 + g);
    float w = __shfl(wl,    jj*8 + g);        // pad lanes weight 0
    uint2 r = ((const uint2*)(xh + (size_t)u*32))[q];     // 8B = 4 bf16
    acc.x = fmaf(w, bfl(r.x), acc.x); acc.y = fmaf(w, bfh(r.x), acc.y);
    acc.z = fmaf(w, bfl(r.y), acc.z); acc.w = fmaf(w, bfh(r.y), acc.w);
  }
  #pragma unroll
  for (int off = 8; off <= 32; off <<= 1){
    acc.x += __shfl_xor(acc.x, off); acc.y += __shfl_xor(acc.y, off);
    acc.z += __shfl_xor(acc.z, off); acc.w += __shfl_xor(acc.w, off);
  }
  float dv = rsqrtf((float)(cn + 1));
  uint2 sr = ((const uint2*)(xh + (size_t)v*32))[q];      // self row
  acc.x = fmaf(dv, bfl(sr.x), acc.x); acc.y = fmaf(dv, bfh(sr.x), acc.y);
  acc.z = fmaf(dv, bfl(sr.y), acc.z); acc.w = fmaf(dv, bfh(sr.y), acc.w);
  float4 res = {acc.x*dv, acc.y*dv, acc.z*dv, acc.w*dv};
  if (lane < 8) ((float4*)(y + (size_t)v*32))[q] = res;   // 128B store
}

// t[v][lane] = relu?(x[v].W[:,lane] * scale? + b?) -> f32 out
template<int K, bool SCALE, bool BRELU>
__global__ __launch_bounds__(256, 4) void k_gemm(const float* __restrict__ x,
                       const float* __restrict__ W, const int* __restrict__ cnt,
                       const float* __restrict__ b, float* __restrict__ t, int n){
  int lane = threadIdx.x & 63;
  int gw = blockIdx.x*4 + uwave();
  int nw = gridDim.x*4;
  float wreg[K];
  #pragma unroll
  for (int k = 0; k < K; k++) wreg[k] = W[k*64 + lane];   // coalesced, once
  float br = BRELU ? b[lane] : 0.f;
  for (int v = gw; v < n; v += nw){                        // uniform loop
    const float4* xr = (const float4*)(x + (size_t)v*K);
    float acc = 0.f;
    #pragma unroll
    for (int k4 = 0; k4 < K/4; k4++){
      float4 xv = xr[k4];                                  // scalarized
      acc = fmaf(xv.x, wreg[k4*4+0], acc);
      acc = fmaf(xv.y, wreg[k4*4+1], acc);
      acc = fmaf(xv.z, wreg[k4*4+2], acc);
      acc = fmaf(xv.w, wreg[k4*4+3], acc);
    }
    if (SCALE) acc *= rsqrtf((float)(cnt[v] + 1));
    if (BRELU) acc = fmaxf(acc + br, 0.f);
    t[(size_t)v*64 + lane] = acc;
  }
}

// K=64 GEMM -> bf16 out (gather source), optional pre-scale by rsqrt(deg)
template<bool SCALE>
__global__ __launch_bounds__(256, 4) void k_gemm_b(const float* __restrict__ x,
                       const float* __restrict__ W, const int* __restrict__ cnt,
                       unsigned short* __restrict__ t, int n){
  int lane = threadIdx.x & 63;
  int gw = blockIdx.x*4 + uwave();
  int nw = gridDim.x*4;
  float wreg[64];
  #pragma unroll
  for (int k = 0; k < 64; k++) wreg[k] = W[k*64 + lane];
  for (int v = gw; v < n; v += nw){
    const float4* xr = (const float4*)(x + (size_t)v*64);
    float acc = 0.f;
    #pragma unroll
    for (int k4 = 0; k4 < 16; k4++){
      float4 xv = xr[k4];
      acc = fmaf(xv.x, wreg[k4*4+0], acc);
      acc = fmaf(xv.y, wreg[k4*4+1], acc);
      acc = fmaf(xv.z, wreg[k4*4+2], acc);
      acc = fmaf(xv.w, wreg[k4*4+3], acc);
    }
    if (SCALE) acc *= rsqrtf((float)(cnt[v] + 1));
    t[(size_t)v*64 + lane] = f2bf(acc);                    // 128B coalesced
  }
}

// K=64 GEMM -> bf16 out + fused alpha_src/alpha_dst dots (f32 scores)
__global__ __launch_bounds__(256, 4) void k_gemm_alpha(const float* __restrict__ x,
                       const float* __restrict__ W,
                       const float* __restrict__ asrc, const float* __restrict__ adst,
                       unsigned short* __restrict__ t, float* __restrict__ als,
                       float* __restrict__ ald, int n){
  int lane = threadIdx.x & 63;
  int gw = blockIdx.x*4 + uwave();
  int nw = gridDim.x*4;
  float wreg[64];
  #pragma unroll
  for (int k = 0; k < 64; k++) wreg[k] = W[k*64 + lane];
  float asr = asrc[lane], adr = adst[lane];
  for (int v = gw; v < n; v += nw){
    const float4* xr = (const float4*)(x + (size_t)v*64);
    float acc = 0.f;
    #pragma unroll
    for (int k4 = 0; k4 < 16; k4++){
      float4 xv = xr[k4];
      acc = fmaf(xv.x, wreg[k4*4+0], acc);
      acc = fmaf(xv.y, wreg[k4*4+1], acc);
      acc = fmaf(xv.z, wreg[k4*4+2], acc);
      acc = fmaf(xv.w, wreg[k4*4+3], acc);
    }
    t[(size_t)v*64 + lane] = f2bf(acc);
    float s1 = acc * asr, s2 = acc * adr;
    #pragma unroll
    for (int off = 32; off; off >>= 1){
      s1 += __shfl_xor(s1, off);
      s2 += __shfl_xor(s2, off);
    }
    if (lane == 0){ als[v] = s1; ald[v] = s2; }
  }
}

// GCN agg (layer 3), bf16 rows: 8 grp x 8 lanes, uint4/lane = 8 rows/instr.
__global__ __launch_bounds__(256) void k_gcn_agg(const unsigned short* __restrict__ t,
                          const int* __restrict__ adj, const int* __restrict__ cnt,
                          const float* __restrict__ b, float* __restrict__ h, int n){
  int lane = threadIdx.x & 63;
  int v = blockIdx.x*4 + uwave();
  if (v >= n) return;                         // uniform
  int cn = cnt[v];
  int c = min(cn, CAP);
  const int* row = adj + (size_t)v*CAP;
  int ureg = n;                               // pad -> zero row
  if (lane < c) ureg = row[lane];
  int g = lane >> 3, q = lane & 7;
  float acc[8] = {0.f,0.f,0.f,0.f,0.f,0.f,0.f,0.f};
  int iters = (c + 7) >> 3;
  for (int jj = 0; jj < iters; jj++){
    int u = __shfl(ureg, jj*8 + g);
    uint4 r = ((const uint4*)(t + (size_t)u*64))[q];      // 16B = 8 bf16
    acc[0] += bfl(r.x); acc[1] += bfh(r.x); acc[2] += bfl(r.y); acc[3] += bfh(r.y);
    acc[4] += bfl(r.z); acc[5] += bfh(r.z); acc[6] += bfl(r.w); acc[7] += bfh(r.w);
  }
  #pragma unroll
  for (int off = 8; off <= 32; off <<= 1){
    #pragma unroll
    for (int k = 0; k < 8; k++) acc[k] += __shfl_xor(acc[k], off);
  }
  uint4 sr = ((const uint4*)(t + (size_t)v*64))[q];       // self row (L2-hot)
  acc[0] += bfl(sr.x); acc[1] += bfh(sr.x); acc[2] += bfl(sr.y); acc[3] += bfh(sr.y);
  acc[4] += bfl(sr.z); acc[5] += bfh(sr.z); acc[6] += bfl(sr.w); acc[7] += bfh(sr.w);
  float dv = rsqrtf((float)(cn + 1));
  float4 b0 = ((const float4*)b)[2*q], b1 = ((const float4*)b)[2*q+1];
  if (lane < 8){
    float4 r0, r1;
    r0.x = fmaxf(fmaf(acc[0], dv, b0.x), 0.f); r0.y = fmaxf(fmaf(acc[1], dv, b0.y), 0.f);
    r0.z = fmaxf(fmaf(acc[2], dv, b0.z), 0.f); r0.w = fmaxf(fmaf(acc[3], dv, b0.w), 0.f);
    r1.x = fmaxf(fmaf(acc[4], dv, b1.x), 0.f); r1.y = fmaxf(fmaf(acc[5], dv, b1.y), 0.f);
    r1.z = fmaxf(fmaf(acc[6], dv, b1.z), 0.f); r1.w = fmaxf(fmaf(acc[7], dv, b1.w), 0.f);
    ((float4*)(h + (size_t)v*64))[2*q]   = r0;            // 256B store
    ((float4*)(h + (size_t)v*64))[2*q+1] = r1;
  }
}

// GAT agg, bf16 rows: softmax over in-edges + analytic self term.
__global__ __launch_bounds__(256) void k_gat_agg(const unsigned short* __restrict__ t,
                          const int* __restrict__ adj, const int* __restrict__ cnt,
                          const float* __restrict__ als, const float* __restrict__ ald,
                          const float* __restrict__ b, float* __restrict__ h, int n){
  int lane = threadIdx.x & 63;
  int v = blockIdx.x*4 + uwave();
  if (v >= n) return;
  int c = min(cnt[v], CAP);
  const int* row = adj + (size_t)v*CAP;
  int ureg = n;                               // pad -> zero row for gather
  if (lane < c) ureg = row[lane];
  int usafe = (lane < c) ? ureg : v;
  float adv = ald[v];                         // uniform
  float e = als[usafe] + adv;                 // 4B gather (lane=edge)
  e = e > 0.f ? e : 0.2f*e;
  float es = als[v] + adv;                    // self score (uniform)
  es = es > 0.f ? es : 0.2f*es;
  float em = (lane < c) ? e : -1e30f;
  #pragma unroll
  for (int off = 32; off; off >>= 1) em = fmaxf(em, __shfl_xor(em, off));
  em = fmaxf(em, es);
  float p = (lane < c) ? __expf(e - em) : 0.f;
  float s = p;
  #pragma unroll
  for (int off = 32; off; off >>= 1) s += __shfl_xor(s, off);
  float ps = __expf(es - em);
  float inv = 1.f / (s + ps);
  int g = lane >> 3, q = lane & 7;
  float acc[8] = {0.f,0.f,0.f,0.f,0.f,0.f,0.f,0.f};
  int iters = (c + 7) >> 3;
  for (int jj = 0; jj < iters; jj++){
    int   u = __shfl(ureg, jj*8 + g);
    float w = __shfl(p,    jj*8 + g);         // pad slots p=0
    uint4 r = ((const uint4*)(t + (size_t)u*64))[q];
    acc[0] = fmaf(w, bfl(r.x), acc[0]); acc[1] = fmaf(w, bfh(r.x), acc[1]);
    acc[2] = fmaf(w, bfl(r.y), acc[2]); acc[3] = fmaf(w, bfh(r.y), acc[3]);
    acc[4] = fmaf(w, bfl(r.z), acc[4]); acc[5] = fmaf(w, bfh(r.z), acc[5]);
    acc[6] = fmaf(w, bfl(r.w), acc[6]); acc[7] = fmaf(w, bfh(r.w), acc[7]);
  }
  #pragma unroll
  for (int off = 8; off <= 32; off <<= 1){
    #pragma unroll
    for (int k = 0; k < 8; k++) acc[k] += __shfl_xor(acc[k], off);
  }
  uint4 sr = ((const uint4*)(t + (size_t)v*64))[q];       // self row
  acc[0] = fmaf(ps, bfl(sr.x), acc[0]); acc[1] = fmaf(ps, bfh(sr.x), acc[1]);
  acc[2] = fmaf(ps, bfl(sr.y), acc[2]); acc[3] = fmaf(ps, bfh(sr.y), acc[3]);
  acc[4] = fmaf(ps, bfl(sr.z), acc[4]); acc[5] = fmaf(ps, bfh(sr.z), acc[5]);
  acc[6] = fmaf(ps, bfl(sr.w), acc[6]); acc[7] = fmaf(ps, bfh(sr.w), acc[7]);
  float4 b0 = ((const float4*)b)[2*q], b1 = ((const float4*)b)[2*q+1];
  if (lane < 8){
    float4 r0, r1;
    r0.x = fmaxf(fmaf(acc[0], inv, b0.x), 0.f); r0.y = fmaxf(fmaf(acc[1], inv, b0.y), 0.f);
    r0.z = fmaxf(fmaf(acc[2], inv, b0.z), 0.f); r0.w = fmaxf(fmaf(acc[3], inv, b0.w), 0.f);
    r1.x = fmaxf(fmaf(acc[4], inv, b1.x), 0.f); r1.y = fmaxf(fmaf(acc[5], inv, b1.y), 0.f);
    r1.z = fmaxf(fmaf(acc[6], inv, b1.z), 0.f); r1.w = fmaxf(fmaf(acc[7], inv, b1.w), 0.f);
    ((float4*)(h + (size_t)v*64))[2*q]   = r0;
    ((float4*)(h + (size_t)v*64))[2*q+1] = r1;
  }
}

// heads: gemm_alpha-mirror structure (dense Wcat/bcat, resident wreg[64]).
__global__ __launch_bounds__(256, 4) void k_heads(const float* __restrict__ h,
                        const float* __restrict__ Wcat, const float* __restrict__ bcat,
                        const float* __restrict__ Wb2, const float* __restrict__ bb2,
                        float* __restrict__ out_opt, float* __restrict__ out_bot, int n){
  int lane = threadIdx.x & 63;
  int gw = blockIdx.x*4 + uwave();
  int nw = gridDim.x*4;
  float wreg[64];
  #pragma unroll
  for (int k = 0; k < 64; k++) wreg[k] = Wcat[k*64 + lane];
  float bcr  = bcat[lane];
  float wb2r = (lane >= 32) ? Wb2[lane-32] : 0.f;
  float bb2r = bb2[0];
  for (int v = gw; v < n; v += nw){
    const float4* xr = (const float4*)(h + (size_t)v*64);
    float acc = bcr;
    #pragma unroll
    for (int k4 = 0; k4 < 16; k4++){
      float4 xv = xr[k4];
      acc = fmaf(xv.x, wreg[k4*4+0], acc);
      acc = fmaf(xv.y, wreg[k4*4+1], acc);
      acc = fmaf(xv.z, wreg[k4*4+2], acc);
      acc = fmaf(xv.w, wreg[k4*4+3], acc);
    }
    if (lane < 10) out_opt[(size_t)v*10 + lane] = acc;
    float contrib = fmaxf(acc, 0.f) * wb2r;   // 0 for lanes<32
    #pragma unroll
    for (int off = 32; off; off >>= 1) contrib += __shfl_xor(contrib, off);
    if (lane == 0) out_bot[v] = 1.f / (1.f + __expf(-(contrib + bb2r)));
  }
}

// mean embedding partials: coalesced stride over h, block-reduce, 64-addr atomics
__global__ __launch_bounds__(256) void k_mean(const float* __restrict__ h,
                       float* __restrict__ emb_acc, int n){
  __shared__ float red[256];
  int tid = threadIdx.x;
  int w = tid >> 6, lane = tid & 63;
  float s = 0.f;
  for (int r = blockIdx.x*4 + w; r < n; r += 1024)
    s += h[(size_t)r*64 + lane];
  red[tid] = s;
  __syncthreads();
  if (tid < 64)
    atomicAdd(&emb_acc[tid], red[tid] + red[64+tid] + red[128+tid] + red[192+tid]);
}

__global__ void k_embed(const float* __restrict__ emb_acc, float* __restrict__ out_emb,
                        float invn){
  if (threadIdx.x < 64) out_emb[threadIdx.x] = emb_acc[threadIdx.x] * invn;
}

extern "C" void kernel_launch(void* const* d_in, const int* in_sizes, int n_in,
                              void* d_out, int out_size, void* d_ws, size_t ws_size,
                              hipStream_t stream) {
  const float* x    = (const float*)d_in[0];
  const int*   ei   = (const int*)d_in[1];
  const float* W1   = (const float*)d_in[2];
  const float* b1   = (const float*)d_in[3];
  const float* W2   = (const float*)d_in[4];
  const float* a_s  = (const float*)d_in[5];
  const float* a_d  = (const float*)d_in[6];
  const float* b2   = (const float*)d_in[7];
  const float* W3   = (const float*)d_in[8];
  const float* b3   = (const float*)d_in[9];
  const float* Wopt = (const float*)d_in[10];
  const float* bopt = (const float*)d_in[11];
  const float* Wb1  = (const float*)d_in[12];
  const float* bb1  = (const float*)d_in[13];
  const float* Wb2  = (const float*)d_in[14];
  const float* bb2  = (const float*)d_in[15];

  int n = in_sizes[0] / 32;      // 100000
  int e = in_sizes[1] / 2;       // 1250000
  const int* src = ei;
  const int* dst = ei + e;

  char* ws = (char*)d_ws;
  size_t off = 0;
  auto alloc = [&](size_t bytes) -> void* {
    void* p = ws + off;
    off += (bytes + 255) & ~(size_t)255;
    return p;
  };
  int*            cnt     = (int*)           alloc((size_t)n * 4);
  int*            adj     = (int*)           alloc((size_t)n * CAP * 4);
  float*          als     = (float*)         alloc((size_t)n * 4);
  float*          ald     = (float*)         alloc((size_t)n * 4);
  unsigned short* xh      = (unsigned short*)alloc((size_t)n * 32 * 2);
  unsigned short* tb      = (unsigned short*)alloc((size_t)(n+1) * 64 * 2); // +zero row n
  float*          hbuf    = (float*)         alloc((size_t)n * 64 * 4);
  float*          emb_acc = (float*)         alloc((size_t)64 * 4);
  float*          Wcat    = (float*)         alloc((size_t)4096 * 4);
  float*          bcat    = (float*)         alloc((size_t)64 * 4);
  int*            ticket  = (int*)           alloc((size_t)8 * 4);
  float*          y1      = (float*)tb;      // alias: y1 dead before t2 written

  float* out_opt = (float*)d_out;
  float* out_bot = out_opt + (size_t)n * 10;
  float* out_emb = out_bot + n;

  int nb4    = (n + 3) / 4;
  int nper   = (n + 7) / 8;
  int total4 = n*32/4;
  int nbS    = (total4 + 255) / 256;
  int nchunk = (e + HCHUNK - 1) / HCHUNK;

  k_setup<<<nbS, 256, 0, stream>>>(x, xh, Wopt, bopt, Wb1, bb1, Wcat, bcat,
                                   cnt, tb, emb_acc, ticket, n, total4);
  k_hist<<<2048, 256, 0, stream>>>(src, dst, cnt, adj, ticket, e, nper, nchunk);

  // layer 1: GCN(32->64): aggregate bf16 x rows -> y1, gemm + bias+relu -> h1
  k_agg32<<<nb4, 256, 0, stream>>>(xh, adj, cnt, y1, n);
  k_gemm<32, false, true><<<1024, 256, 0, stream>>>(y1, W1, cnt, b1, hbuf, n);

  // layer 2: GAT(64->64): gemm -> bf16 t2 + scores, softmax-gather -> h2
  k_gemm_alpha<<<1024, 256, 0, stream>>>(hbuf, W2, a_s, a_d, tb, als, ald, n);
  k_gat_agg<<<nb4, 256, 0, stream>>>(tb, adj, cnt, als, ald, b2, hbuf, n);

  // layer 3: GCN(64->64): gemm (pre-scaled) -> bf16 t3, gather -> h3
  k_gemm_b<true><<<1024, 256, 0, stream>>>(hbuf, W3, cnt, tb, n);
  k_gcn_agg<<<nb4, 256, 0, stream>>>(tb, adj, cnt, b3, hbuf, n);

  // heads, mean, final scale
  k_heads<<<1024, 256, 0, stream>>>(hbuf, Wcat, bcat, Wb2, bb2,
                                    out_opt, out_bot, n);
  k_mean<<<256, 256, 0, stream>>>(hbuf, emb_acc, n);
  k_embed<<<1, 64, 0, stream>>>(emb_acc, out_emb, 1.0f / (float)n);
}

// Round 13
// 429.825 us; speedup vs baseline: 1.6152x; 1.6152x over previous
//
#include <hip/hip_runtime.h>
#include <hip/hip_bf16.h>

// WorkflowGNN: GCN(32->64)+ReLU, GAT(64->64,h=1)+ReLU, GCN(64->64)+ReLU,
// heads: opt [N,10], bottleneck [N,1], mean-embed [64]. f32 in/out.
// R12->R13: REVERT hist to R11 (ticket/XCC version 5x'd it; and WRITE stayed
// 50MB under exact XCD locality -> scatter write-combining floor, accept 62us).
// NEW: layer-1 gemm fused into k_agg32 epilogue (all lanes hold the full
// 32-vec after butterfly; 32 shfl + 32 FMA -> h1 directly). Kills y1
// write+read (25.6MB) and one dispatch, no new workspace.

#define CAP 64

__device__ __forceinline__ int uwave(){                 // wave id, known-uniform
  return __builtin_amdgcn_readfirstlane(threadIdx.x >> 6);
}
__device__ __forceinline__ unsigned short f2bf(float f){ // RNE, finite inputs
  unsigned u = __float_as_uint(f);
  return (unsigned short)((u + 0x7fffu + ((u >> 16) & 1u)) >> 16);
}
__device__ __forceinline__ float bfl(unsigned u){ return __uint_as_float(u << 16); }
__device__ __forceinline__ float bfh(unsigned u){ return __uint_as_float(u & 0xffff0000u); }

// fused setup: zero cnt/pad-row/emb_acc, cast x->bf16, pack Wcat/bcat
__global__ void k_setup(const float* __restrict__ x, unsigned short* __restrict__ xh,
                        const float* __restrict__ Wopt, const float* __restrict__ bopt,
                        const float* __restrict__ Wb1, const float* __restrict__ bb1,
                        float* __restrict__ Wcat, float* __restrict__ bcat,
                        int* __restrict__ cnt, unsigned short* __restrict__ tb,
                        float* __restrict__ emb_acc, int n, int total4){
  int i = blockIdx.x*blockDim.x + threadIdx.x;
  if (i < total4){                            // cast x (f32x4 -> bf16x4)
    float4 v = ((const float4*)x)[i];
    uint2 o;
    o.x = (unsigned)f2bf(v.x) | ((unsigned)f2bf(v.y) << 16);
    o.y = (unsigned)f2bf(v.z) | ((unsigned)f2bf(v.w) << 16);
    ((uint2*)xh)[i] = o;
  }
  if (i < n) cnt[i] = 0;
  if (blockIdx.x == 0){
    int tid = threadIdx.x;
    for (int j = tid; j < 4096; j += 256){    // pack head weights
      int f = j >> 6, c = j & 63;
      float w = 0.f;
      if (c < 10)       w = Wopt[f*10 + c];
      else if (c >= 32) w = Wb1[f*32 + (c-32)];
      Wcat[j] = w;
    }
    if (tid < 64){
      float b = 0.f;
      if (tid < 10)       b = bopt[tid];
      else if (tid >= 32) b = bb1[tid-32];
      bcat[tid] = b;
      tb[(size_t)n*64 + tid] = 0;             // zero pad row
      emb_acc[tid] = 0.f;
    }
  }
}

// R11 histogram: XCD-sliced by blockIdx&7, nt loads for the edge stream.
__global__ void k_hist(const int* __restrict__ src, const int* __restrict__ dst,
                       int* __restrict__ cnt, int* __restrict__ adj,
                       int e, int nper){
  int slice = blockIdx.x & 7;
  int i = (blockIdx.x >> 3)*blockDim.x + threadIdx.x;
  if (i >= e) return;
  int d = __builtin_nontemporal_load(&dst[i]);
  int lo = slice*nper;
  if (d < lo || d >= lo + nper) return;
  int pos = atomicAdd(&cnt[d], 1);
  if (pos < CAP){
    int sv = __builtin_nontemporal_load(&src[i]);
    adj[(size_t)d*CAP + pos] = sv;
  }
}

// layer-1 FUSED aggregate+gemm: gather bf16 x rows (8 grp x 8 lanes, 8 rows
// per uint2 instruction), butterfly-reduce (all lanes end with the full
// 32-vec), then epilogue h1[v][lane] = relu( y . W1[:,lane] + b1[lane] ).
__global__ __launch_bounds__(256) void k_agg32g(const unsigned short* __restrict__ xh,
                          const int* __restrict__ adj, const int* __restrict__ cnt,
                          const float* __restrict__ W1, const float* __restrict__ b1,
                          float* __restrict__ h, int n){
  int lane = threadIdx.x & 63;
  float wreg[32];
  #pragma unroll
  for (int k = 0; k < 32; k++) wreg[k] = W1[k*64 + lane];  // coalesced, once
  float br = b1[lane];
  int v = blockIdx.x*4 + uwave();
  if (v >= n) return;                         // uniform
  int cn = cnt[v];
  int c = min(cn, CAP);
  const int* row = adj + (size_t)v*CAP;
  int usafe = v;
  if (lane < c) usafe = row[lane];            // exec-masked coalesced
  float wl = (lane < c) ? rsqrtf((float)(cnt[usafe] + 1)) : 0.f;  // dinv_u
  int g = lane >> 3, q = lane & 7;
  float4 acc = {0.f, 0.f, 0.f, 0.f};
  int iters = (c + 7) >> 3;
  for (int jj = 0; jj < iters; jj++){
    int   u = __shfl(usafe, jj*8 + g);
    float w = __shfl(wl,    jj*8 + g);        // pad lanes weight 0
    uint2 r = ((const uint2*)(xh + (size_t)u*32))[q];     // 8B = 4 bf16
    acc.x = fmaf(w, bfl(r.x), acc.x); acc.y = fmaf(w, bfh(r.x), acc.y);
    acc.z = fmaf(w, bfl(r.y), acc.z); acc.w = fmaf(w, bfh(r.y), acc.w);
  }
  #pragma unroll
  for (int off = 8; off <= 32; off <<= 1){
    acc.x += __shfl_xor(acc.x, off); acc.y += __shfl_xor(acc.y, off);
    acc.z += __shfl_xor(acc.z, off); acc.w += __shfl_xor(acc.w, off);
  }
  float dv = rsqrtf((float)(cn + 1));
  uint2 sr = ((const uint2*)(xh + (size_t)v*32))[q];      // self row
  acc.x = fmaf(dv, bfl(sr.x), acc.x); acc.y = fmaf(dv, bfh(sr.x), acc.y);
  acc.z = fmaf(dv, bfl(sr.y), acc.z); acc.w = fmaf(dv, bfh(sr.y), acc.w);
  acc.x *= dv; acc.y *= dv; acc.z *= dv; acc.w *= dv;     // y elements 4q..4q+3
  // epilogue gemm: broadcast y from lanes 0..7, dot with wreg
  float hacc = br;
  #pragma unroll
  for (int q2 = 0; q2 < 8; q2++){
    float4 vv;
    vv.x = __shfl(acc.x, q2); vv.y = __shfl(acc.y, q2);
    vv.z = __shfl(acc.z, q2); vv.w = __shfl(acc.w, q2);
    hacc = fmaf(vv.x, wreg[q2*4+0], hacc);
    hacc = fmaf(vv.y, wreg[q2*4+1], hacc);
    hacc = fmaf(vv.z, wreg[q2*4+2], hacc);
    hacc = fmaf(vv.w, wreg[q2*4+3], hacc);
  }
  h[(size_t)v*64 + lane] = fmaxf(hacc, 0.f);  // coalesced 256B
}

// K=64 GEMM -> bf16 out (gather source), optional pre-scale by rsqrt(deg)
template<bool SCALE>
__global__ __launch_bounds__(256, 4) void k_gemm_b(const float* __restrict__ x,
                       const float* __restrict__ W, const int* __restrict__ cnt,
                       unsigned short* __restrict__ t, int n){
  int lane = threadIdx.x & 63;
  int gw = blockIdx.x*4 + uwave();
  int nw = gridDim.x*4;
  float wreg[64];
  #pragma unroll
  for (int k = 0; k < 64; k++) wreg[k] = W[k*64 + lane];
  for (int v = gw; v < n; v += nw){
    const float4* xr = (const float4*)(x + (size_t)v*64);
    float acc = 0.f;
    #pragma unroll
    for (int k4 = 0; k4 < 16; k4++){
      float4 xv = xr[k4];
      acc = fmaf(xv.x, wreg[k4*4+0], acc);
      acc = fmaf(xv.y, wreg[k4*4+1], acc);
      acc = fmaf(xv.z, wreg[k4*4+2], acc);
      acc = fmaf(xv.w, wreg[k4*4+3], acc);
    }
    if (SCALE) acc *= rsqrtf((float)(cnt[v] + 1));
    t[(size_t)v*64 + lane] = f2bf(acc);                    // 128B coalesced
  }
}

// K=64 GEMM -> bf16 out + fused alpha_src/alpha_dst dots (f32 scores)
__global__ __launch_bounds__(256, 4) void k_gemm_alpha(const float* __restrict__ x,
                       const float* __restrict__ W,
                       const float* __restrict__ asrc, const float* __restrict__ adst,
                       unsigned short* __restrict__ t, float* __restrict__ als,
                       float* __restrict__ ald, int n){
  int lane = threadIdx.x & 63;
  int gw = blockIdx.x*4 + uwave();
  int nw = gridDim.x*4;
  float wreg[64];
  #pragma unroll
  for (int k = 0; k < 64; k++) wreg[k] = W[k*64 + lane];
  float asr = asrc[lane], adr = adst[lane];
  for (int v = gw; v < n; v += nw){
    const float4* xr = (const float4*)(x + (size_t)v*64);
    float acc = 0.f;
    #pragma unroll
    for (int k4 = 0; k4 < 16; k4++){
      float4 xv = xr[k4];
      acc = fmaf(xv.x, wreg[k4*4+0], acc);
      acc = fmaf(xv.y, wreg[k4*4+1], acc);
      acc = fmaf(xv.z, wreg[k4*4+2], acc);
      acc = fmaf(xv.w, wreg[k4*4+3], acc);
    }
    t[(size_t)v*64 + lane] = f2bf(acc);
    float s1 = acc * asr, s2 = acc * adr;
    #pragma unroll
    for (int off = 32; off; off >>= 1){
      s1 += __shfl_xor(s1, off);
      s2 += __shfl_xor(s2, off);
    }
    if (lane == 0){ als[v] = s1; ald[v] = s2; }
  }
}

// GCN agg (layer 3), bf16 rows: 8 grp x 8 lanes, uint4/lane = 8 rows/instr.
__global__ __launch_bounds__(256) void k_gcn_agg(const unsigned short* __restrict__ t,
                          const int* __restrict__ adj, const int* __restrict__ cnt,
                          const float* __restrict__ b, float* __restrict__ h, int n){
  int lane = threadIdx.x & 63;
  int v = blockIdx.x*4 + uwave();
  if (v >= n) return;                         // uniform
  int cn = cnt[v];
  int c = min(cn, CAP);
  const int* row = adj + (size_t)v*CAP;
  int ureg = n;                               // pad -> zero row
  if (lane < c) ureg = row[lane];
  int g = lane >> 3, q = lane & 7;
  float acc[8] = {0.f,0.f,0.f,0.f,0.f,0.f,0.f,0.f};
  int iters = (c + 7) >> 3;
  for (int jj = 0; jj < iters; jj++){
    int u = __shfl(ureg, jj*8 + g);
    uint4 r = ((const uint4*)(t + (size_t)u*64))[q];      // 16B = 8 bf16
    acc[0] += bfl(r.x); acc[1] += bfh(r.x); acc[2] += bfl(r.y); acc[3] += bfh(r.y);
    acc[4] += bfl(r.z); acc[5] += bfh(r.z); acc[6] += bfl(r.w); acc[7] += bfh(r.w);
  }
  #pragma unroll
  for (int off = 8; off <= 32; off <<= 1){
    #pragma unroll
    for (int k = 0; k < 8; k++) acc[k] += __shfl_xor(acc[k], off);
  }
  uint4 sr = ((const uint4*)(t + (size_t)v*64))[q];       // self row (L2-hot)
  acc[0] += bfl(sr.x); acc[1] += bfh(sr.x); acc[2] += bfl(sr.y); acc[3] += bfh(sr.y);
  acc[4] += bfl(sr.z); acc[5] += bfh(sr.z); acc[6] += bfl(sr.w); acc[7] += bfh(sr.w);
  float dv = rsqrtf((float)(cn + 1));
  float4 b0 = ((const float4*)b)[2*q], b1 = ((const float4*)b)[2*q+1];
  if (lane < 8){
    float4 r0, r1;
    r0.x = fmaxf(fmaf(acc[0], dv, b0.x), 0.f); r0.y = fmaxf(fmaf(acc[1], dv, b0.y), 0.f);
    r0.z = fmaxf(fmaf(acc[2], dv, b0.z), 0.f); r0.w = fmaxf(fmaf(acc[3], dv, b0.w), 0.f);
    r1.x = fmaxf(fmaf(acc[4], dv, b1.x), 0.f); r1.y = fmaxf(fmaf(acc[5], dv, b1.y), 0.f);
    r1.z = fmaxf(fmaf(acc[6], dv, b1.z), 0.f); r1.w = fmaxf(fmaf(acc[7], dv, b1.w), 0.f);
    ((float4*)(h + (size_t)v*64))[2*q]   = r0;            // 256B store
    ((float4*)(h + (size_t)v*64))[2*q+1] = r1;
  }
}

// GAT agg, bf16 rows: softmax over in-edges + analytic self term.
__global__ __launch_bounds__(256) void k_gat_agg(const unsigned short* __restrict__ t,
                          const int* __restrict__ adj, const int* __restrict__ cnt,
                          const float* __restrict__ als, const float* __restrict__ ald,
                          const float* __restrict__ b, float* __restrict__ h, int n){
  int lane = threadIdx.x & 63;
  int v = blockIdx.x*4 + uwave();
  if (v >= n) return;
  int c = min(cnt[v], CAP);
  const int* row = adj + (size_t)v*CAP;
  int ureg = n;                               // pad -> zero row for gather
  if (lane < c) ureg = row[lane];
  int usafe = (lane < c) ? ureg : v;
  float adv = ald[v];                         // uniform
  float e = als[usafe] + adv;                 // 4B gather (lane=edge)
  e = e > 0.f ? e : 0.2f*e;
  float es = als[v] + adv;                    // self score (uniform)
  es = es > 0.f ? es : 0.2f*es;
  float em = (lane < c) ? e : -1e30f;
  #pragma unroll
  for (int off = 32; off; off >>= 1) em = fmaxf(em, __shfl_xor(em, off));
  em = fmaxf(em, es);
  float p = (lane < c) ? __expf(e - em) : 0.f;
  float s = p;
  #pragma unroll
  for (int off = 32; off; off >>= 1) s += __shfl_xor(s, off);
  float ps = __expf(es - em);
  float inv = 1.f / (s + ps);
  int g = lane >> 3, q = lane & 7;
  float acc[8] = {0.f,0.f,0.f,0.f,0.f,0.f,0.f,0.f};
  int iters = (c + 7) >> 3;
  for (int jj = 0; jj < iters; jj++){
    int   u = __shfl(ureg, jj*8 + g);
    float w = __shfl(p,    jj*8 + g);         // pad slots p=0
    uint4 r = ((const uint4*)(t + (size_t)u*64))[q];
    acc[0] = fmaf(w, bfl(r.x), acc[0]); acc[1] = fmaf(w, bfh(r.x), acc[1]);
    acc[2] = fmaf(w, bfl(r.y), acc[2]); acc[3] = fmaf(w, bfh(r.y), acc[3]);
    acc[4] = fmaf(w, bfl(r.z), acc[4]); acc[5] = fmaf(w, bfh(r.z), acc[5]);
    acc[6] = fmaf(w, bfl(r.w), acc[6]); acc[7] = fmaf(w, bfh(r.w), acc[7]);
  }
  #pragma unroll
  for (int off = 8; off <= 32; off <<= 1){
    #pragma unroll
    for (int k = 0; k < 8; k++) acc[k] += __shfl_xor(acc[k], off);
  }
  uint4 sr = ((const uint4*)(t + (size_t)v*64))[q];       // self row
  acc[0] = fmaf(ps, bfl(sr.x), acc[0]); acc[1] = fmaf(ps, bfh(sr.x), acc[1]);
  acc[2] = fmaf(ps, bfl(sr.y), acc[2]); acc[3] = fmaf(ps, bfh(sr.y), acc[3]);
  acc[4] = fmaf(ps, bfl(sr.z), acc[4]); acc[5] = fmaf(ps, bfh(sr.z), acc[5]);
  acc[6] = fmaf(ps, bfl(sr.w), acc[6]); acc[7] = fmaf(ps, bfh(sr.w), acc[7]);
  float4 b0 = ((const float4*)b)[2*q], b1 = ((const float4*)b)[2*q+1];
  if (lane < 8){
    float4 r0, r1;
    r0.x = fmaxf(fmaf(acc[0], inv, b0.x), 0.f); r0.y = fmaxf(fmaf(acc[1], inv, b0.y), 0.f);
    r0.z = fmaxf(fmaf(acc[2], inv, b0.z), 0.f); r0.w = fmaxf(fmaf(acc[3], inv, b0.w), 0.f);
    r1.x = fmaxf(fmaf(acc[4], inv, b1.x), 0.f); r1.y = fmaxf(fmaf(acc[5], inv, b1.y), 0.f);
    r1.z = fmaxf(fmaf(acc[6], inv, b1.z), 0.f); r1.w = fmaxf(fmaf(acc[7], inv, b1.w), 0.f);
    ((float4*)(h + (size_t)v*64))[2*q]   = r0;
    ((float4*)(h + (size_t)v*64))[2*q+1] = r1;
  }
}

// heads: gemm_alpha-mirror structure (dense Wcat/bcat, resident wreg[64]).
__global__ __launch_bounds__(256, 4) void k_heads(const float* __restrict__ h,
                        const float* __restrict__ Wcat, const float* __restrict__ bcat,
                        const float* __restrict__ Wb2, const float* __restrict__ bb2,
                        float* __restrict__ out_opt, float* __restrict__ out_bot, int n){
  int lane = threadIdx.x & 63;
  int gw = blockIdx.x*4 + uwave();
  int nw = gridDim.x*4;
  float wreg[64];
  #pragma unroll
  for (int k = 0; k < 64; k++) wreg[k] = Wcat[k*64 + lane];
  float bcr  = bcat[lane];
  float wb2r = (lane >= 32) ? Wb2[lane-32] : 0.f;
  float bb2r = bb2[0];
  for (int v = gw; v < n; v += nw){
    const float4* xr = (const float4*)(h + (size_t)v*64);
    float acc = bcr;
    #pragma unroll
    for (int k4 = 0; k4 < 16; k4++){
      float4 xv = xr[k4];
      acc = fmaf(xv.x, wreg[k4*4+0], acc);
      acc = fmaf(xv.y, wreg[k4*4+1], acc);
      acc = fmaf(xv.z, wreg[k4*4+2], acc);
      acc = fmaf(xv.w, wreg[k4*4+3], acc);
    }
    if (lane < 10) out_opt[(size_t)v*10 + lane] = acc;
    float contrib = fmaxf(acc, 0.f) * wb2r;   // 0 for lanes<32
    #pragma unroll
    for (int off = 32; off; off >>= 1) contrib += __shfl_xor(contrib, off);
    if (lane == 0) out_bot[v] = 1.f / (1.f + __expf(-(contrib + bb2r)));
  }
}

// mean embedding partials: coalesced stride over h, block-reduce, 64-addr atomics
__global__ __launch_bounds__(256) void k_mean(const float* __restrict__ h,
                       float* __restrict__ emb_acc, int n){
  __shared__ float red[256];
  int tid = threadIdx.x;
  int w = tid >> 6, lane = tid & 63;
  float s = 0.f;
  for (int r = blockIdx.x*4 + w; r < n; r += 1024)
    s += h[(size_t)r*64 + lane];
  red[tid] = s;
  __syncthreads();
  if (tid < 64)
    atomicAdd(&emb_acc[tid], red[tid] + red[64+tid] + red[128+tid] + red[192+tid]);
}

__global__ void k_embed(const float* __restrict__ emb_acc, float* __restrict__ out_emb,
                        float invn){
  if (threadIdx.x < 64) out_emb[threadIdx.x] = emb_acc[threadIdx.x] * invn;
}

extern "C" void kernel_launch(void* const* d_in, const int* in_sizes, int n_in,
                              void* d_out, int out_size, void* d_ws, size_t ws_size,
                              hipStream_t stream) {
  const float* x    = (const float*)d_in[0];
  const int*   ei   = (const int*)d_in[1];
  const float* W1   = (const float*)d_in[2];
  const float* b1   = (const float*)d_in[3];
  const float* W2   = (const float*)d_in[4];
  const float* a_s  = (const float*)d_in[5];
  const float* a_d  = (const float*)d_in[6];
  const float* b2   = (const float*)d_in[7];
  const float* W3   = (const float*)d_in[8];
  const float* b3   = (const float*)d_in[9];
  const float* Wopt = (const float*)d_in[10];
  const float* bopt = (const float*)d_in[11];
  const float* Wb1  = (const float*)d_in[12];
  const float* bb1  = (const float*)d_in[13];
  const float* Wb2  = (const float*)d_in[14];
  const float* bb2  = (const float*)d_in[15];

  int n = in_sizes[0] / 32;      // 100000
  int e = in_sizes[1] / 2;       // 1250000
  const int* src = ei;
  const int* dst = ei + e;

  char* ws = (char*)d_ws;
  size_t off = 0;
  auto alloc = [&](size_t bytes) -> void* {
    void* p = ws + off;
    off += (bytes + 255) & ~(size_t)255;
    return p;
  };
  int*            cnt     = (int*)           alloc((size_t)n * 4);
  int*            adj     = (int*)           alloc((size_t)n * CAP * 4);
  float*          als     = (float*)         alloc((size_t)n * 4);
  float*          ald     = (float*)         alloc((size_t)n * 4);
  unsigned short* xh      = (unsigned short*)alloc((size_t)n * 32 * 2);
  unsigned short* tb      = (unsigned short*)alloc((size_t)(n+1) * 64 * 2); // +zero row n
  float*          hbuf    = (float*)         alloc((size_t)n * 64 * 4);
  float*          emb_acc = (float*)         alloc((size_t)64 * 4);
  float*          Wcat    = (float*)         alloc((size_t)4096 * 4);
  float*          bcat    = (float*)         alloc((size_t)64 * 4);

  float* out_opt = (float*)d_out;
  float* out_bot = out_opt + (size_t)n * 10;
  float* out_emb = out_bot + n;

  int nb4    = (n + 3) / 4;
  int nbE    = (e + 255) / 256;
  int nper   = (n + 7) / 8;
  int total4 = n*32/4;
  int nbS    = (total4 + 255) / 256;

  k_setup<<<nbS, 256, 0, stream>>>(x, xh, Wopt, bopt, Wb1, bb1, Wcat, bcat,
                                   cnt, tb, emb_acc, n, total4);
  k_hist<<<nbE*8, 256, 0, stream>>>(src, dst, cnt, adj, e, nper);

  // layer 1: GCN(32->64) fully fused: gather bf16 x + epilogue gemm -> h1
  k_agg32g<<<nb4, 256, 0, stream>>>(xh, adj, cnt, W1, b1, hbuf, n);

  // layer 2: GAT(64->64): gemm -> bf16 t2 + scores, softmax-gather -> h2
  k_gemm_alpha<<<1024, 256, 0, stream>>>(hbuf, W2, a_s, a_d, tb, als, ald, n);
  k_gat_agg<<<nb4, 256, 0, stream>>>(tb, adj, cnt, als, ald, b2, hbuf, n);

  // layer 3: GCN(64->64): gemm (pre-scaled) -> bf16 t3, gather -> h3
  k_gemm_b<true><<<1024, 256, 0, stream>>>(hbuf, W3, cnt, tb, n);
  k_gcn_agg<<<nb4, 256, 0, stream>>>(tb, adj, cnt, b3, hbuf, n);

  // heads, mean, final scale
  k_heads<<<1024, 256, 0, stream>>>(hbuf, Wcat, bcat, Wb2, bb2,
                                    out_opt, out_bot, n);
  k_mean<<<256, 256, 0, stream>>>(hbuf, emb_acc, n);
  k_embed<<<1, 64, 0, stream>>>(emb_acc, out_emb, 1.0f / (float)n);
}